// Round 2
// baseline (14767.615 us; speedup 1.0000x reference)
//
#include <hip/hip_runtime.h>

// =====================================================================
// fp32 ops emulated as plain bf16 GEMMs with K doubled (hi/lo split):
//   x = hi + lo (hi = RNE bf16, lo = bf16 residual);  A*B over K'=2K
//   reproduces fp32 product to ~2^-16 relative (bf16x4).
// All operands pre-split OUTSIDE the GEMM (producers emit split form).
// MFMA v_mfma_f32_16x16x32_bf16; A/B fragments use the same k-bijection
// (k = (lane>>4)*8+e) -> correct for any internal hw k-permutation
// (validated by round-1 pass). C/D: col=lane&15, row=(lane>>4)*4+reg.
// LDS tiles [rows][64]u16 with 16B-granule XOR swizzle (g ^= row&7):
// conflict-free ds_read_b128 / ds_write_b128.
// =====================================================================

typedef unsigned short u16;
typedef unsigned int   u32;
typedef __attribute__((ext_vector_type(4))) float f32x4;
typedef __attribute__((ext_vector_type(8))) short bf16x8;

__device__ __forceinline__ u32 bf16hi_bits(float x) {
    u32 u = __float_as_uint(x);
    return (u + 0x7FFFu + ((u >> 16) & 1u)) & 0xFFFF0000u;   // RNE to bf16
}
__device__ __forceinline__ void split1(float x, u16& h, u16& l) {
    u32 hh = bf16hi_bits(x);
    h = (u16)(hh >> 16);
    float r = x - __uint_as_float(hh);                        // exact residual
    l = (u16)(__float_as_uint(r) >> 16);                      // truncate to bf16
}

// ---------------- tile staging: NROWS x 64 u16, swizzled ----------------
template<int NROWS>
__device__ __forceinline__ void tile_loads(const u16* __restrict__ src, int ld16, int kb16,
                                           int w, int lane, uint4* regs) {
    const int r0 = w * (NROWS / 4);
    const int rr = lane >> 3, g = lane & 7;
#pragma unroll
    for (int it = 0; it < NROWS / 32; ++it) {
        const int r = r0 + it * 8 + rr;
        regs[it] = *(const uint4*)(src + (size_t)r * ld16 + kb16 + g * 8);
    }
}
template<int NROWS>
__device__ __forceinline__ void tile_writes(u16 (*T)[64], int w, int lane, const uint4* regs) {
    const int r0 = w * (NROWS / 4);
    const int rr = lane >> 3, g = lane & 7;
#pragma unroll
    for (int it = 0; it < NROWS / 32; ++it) {
        const int r = r0 + it * 8 + rr;
        *(uint4*)&T[r][(g ^ (r & 7)) * 8] = regs[it];
    }
}

// ---------------- MFMA over one K-step (64 u16 k-elems) ----------------
template<int MI>
__device__ __forceinline__ void tile_mma(const u16 (*As)[64], const u16 (*Bs)[64],
                                         int mrow0, int ncol0, int lane, f32x4 acc[][4]) {
    const int lr = lane & 15, lg = lane >> 4;
#pragma unroll
    for (int kh = 0; kh < 2; ++kh) {
        bf16x8 bf[4];
#pragma unroll
        for (int j = 0; j < 4; ++j) {
            const int n = ncol0 + j * 16 + lr;
            bf[j] = *(const bf16x8*)&Bs[n][((kh * 4 + lg) ^ (n & 7)) * 8];
        }
#pragma unroll
        for (int i = 0; i < MI; ++i) {
            const int m = mrow0 + i * 16 + lr;
            bf16x8 af = *(const bf16x8*)&As[m][((kh * 4 + lg) ^ (m & 7)) * 8];
#pragma unroll
            for (int j = 0; j < 4; ++j)
                acc[i][j] = __builtin_amdgcn_mfma_f32_16x16x32_bf16(af, bf[j], acc[i][j], 0, 0, 0);
        }
    }
}

#define TILE_PROLOGUE(BN)                                                     \
    const int lane = threadIdx.x & 63, w = threadIdx.x >> 6;                  \
    constexpr int MI = (BN == 128) ? 4 : 2;                                   \
    const int mrow0 = (BN == 128) ? (w >> 1) * 64 : w * 32;                   \
    const int ncol0 = (BN == 128) ? (w & 1) * 64 : 0;                         \
    f32x4 acc[MI][4];                                                         \
    {                                                                         \
        f32x4 z4 = {0.f, 0.f, 0.f, 0.f};                                      \
        _Pragma("unroll") for (int i = 0; i < MI; ++i)                        \
            _Pragma("unroll") for (int j = 0; j < 4; ++j) acc[i][j] = z4;     \
    }

#define TILE_KLOOP(BN)                                                        \
    uint4 pa[4], pb[BN / 32];                                                 \
    tile_loads<128>(Ab, lda16, 0, w, lane, pa);                               \
    tile_loads<BN>(Bb, ldb16, 0, w, lane, pb);                                \
    for (int kb = 0; kb < K16; kb += 64) {                                    \
        __syncthreads();                                                      \
        tile_writes<128>(As, w, lane, pa);                                    \
        tile_writes<BN>(Bs, w, lane, pb);                                     \
        __syncthreads();                                                      \
        if (kb + 64 < K16) {                                                  \
            tile_loads<128>(Ab, lda16, kb + 64, w, lane, pa);                 \
            tile_loads<BN>(Bb, ldb16, kb + 64, w, lane, pb);                  \
        }                                                                     \
        tile_mma<MI>(As, Bs, mrow0, ncol0, lane, acc);                        \
    }

// =====================================================================
// GEMM -> f32 out (+bias, optional residual, optional N-guard)
// =====================================================================
template<int BN, int RES, int GUARDN>
__global__ __launch_bounds__(256, 2)
void gemm_f32out(const u16* __restrict__ A, int lda16,
                 const u16* __restrict__ B, int ldb16,
                 const float* __restrict__ bias,
                 const float* __restrict__ res, int ldres,
                 float* __restrict__ C, int ldc,
                 int K16, int Nvalid) {
    __shared__ __align__(16) u16 As[128][64];
    __shared__ __align__(16) u16 Bs[BN][64];
    const int m0 = blockIdx.y * 128, n0 = blockIdx.x * BN;
    const u16* Ab = A + (size_t)m0 * lda16;
    const u16* Bb = B + (size_t)n0 * ldb16;
    TILE_PROLOGUE(BN)
    TILE_KLOOP(BN)
    const int lr = lane & 15, lq = lane >> 4;
#pragma unroll
    for (int i = 0; i < MI; ++i) {
        const int m = m0 + mrow0 + i * 16 + lq * 4;
#pragma unroll
        for (int j = 0; j < 4; ++j) {
            const int n = n0 + ncol0 + j * 16 + lr;
            if (!GUARDN || n < Nvalid) {
                const float bz = bias[n];
#pragma unroll
                for (int r = 0; r < 4; ++r) {
                    float vv = acc[i][j][r] + bz;
                    if (RES) vv += res[(size_t)(m + r) * ldres + n];
                    C[(size_t)(m + r) * ldc + n] = vv;
                }
            }
        }
    }
}

// =====================================================================
// GEMM -> split u16 out with ReLU (FF1): C16[m][n]=hi, C16[m][N+n]=lo
// =====================================================================
__global__ __launch_bounds__(256, 2)
void gemm_ff1(const u16* __restrict__ A, int lda16,
              const u16* __restrict__ B, int ldb16,
              const float* __restrict__ bias,
              u16* __restrict__ C16, int N, int K16) {
    constexpr int BN = 128;
    __shared__ __align__(16) u16 As[128][64];
    __shared__ __align__(16) u16 Bs[BN][64];
    const int m0 = blockIdx.y * 128, n0 = blockIdx.x * BN;
    const u16* Ab = A + (size_t)m0 * lda16;
    const u16* Bb = B + (size_t)n0 * ldb16;
    TILE_PROLOGUE(BN)
    TILE_KLOOP(BN)
    const int lr = lane & 15, lq = lane >> 4;
    const int ldc16 = 2 * N;
#pragma unroll
    for (int i = 0; i < MI; ++i) {
        const int m = m0 + mrow0 + i * 16 + lq * 4;
#pragma unroll
        for (int j = 0; j < 4; ++j) {
            const int n = n0 + ncol0 + j * 16 + lr;
            const float bz = bias[n];
#pragma unroll
            for (int r = 0; r < 4; ++r) {
                float vv = acc[i][j][r] + bz;
                vv = vv > 0.f ? vv : 0.f;
                u16 hh, ll; split1(vv, hh, ll);
                u16* row = C16 + (size_t)(m + r) * ldc16;
                row[n] = hh;
                row[N + n] = ll;
            }
        }
    }
}

// =====================================================================
// Fused QKV-style GEMM. which = (global n)>>9 selects output slot
// (slots 8MB apart). which==VWHICH -> plain f32 [M][512]; else split
// head-interleaved u16 [M][1024]: head h=(n&511)>>6, d=n&63:
// hi at h*128+d, lo at h*128+64+d.
// =====================================================================
template<int BN, int VWHICH>
__global__ __launch_bounds__(256, 2)
void gemm_qkv(const u16* __restrict__ A, int lda16,
              const u16* __restrict__ B, int ldb16,
              const float* __restrict__ bias,
              char* __restrict__ Cbase, int K16) {
    __shared__ __align__(16) u16 As[128][64];
    __shared__ __align__(16) u16 Bs[BN][64];
    const int m0 = blockIdx.y * 128, n0 = blockIdx.x * BN;
    const u16* Ab = A + (size_t)m0 * lda16;
    const u16* Bb = B + (size_t)n0 * ldb16;
    TILE_PROLOGUE(BN)
    TILE_KLOOP(BN)
    const int lr = lane & 15, lq = lane >> 4;
    const int which = n0 >> 9;
    char* slot = Cbase + (size_t)which * 8388608;
#pragma unroll
    for (int i = 0; i < MI; ++i) {
        const int m = m0 + mrow0 + i * 16 + lq * 4;
#pragma unroll
        for (int j = 0; j < 4; ++j) {
            const int nf = n0 + ncol0 + j * 16 + lr;
            const int nl = nf & 511;
            const float bz = bias[nf];
            if (which == VWHICH) {
                float* Cf = (float*)slot;
#pragma unroll
                for (int r = 0; r < 4; ++r)
                    Cf[(size_t)(m + r) * 512 + nl] = acc[i][j][r] + bz;
            } else {
                u16* Cu = (u16*)slot;
                const int hh = nl >> 6, d = nl & 63;
#pragma unroll
                for (int r = 0; r < 4; ++r) {
                    u16 vh, vl; split1(acc[i][j][r] + bz, vh, vl);
                    u16* row = Cu + (size_t)(m + r) * 1024 + hh * 128 + d;
                    row[0]  = vh;
                    row[64] = vl;
                }
            }
        }
    }
}

// =====================================================================
// Attention scores: per (z=local bh): S = Q_h K_h^T / 8, masked, f32
// q16/k16 head-interleaved split [rows][1024]; K'=128.
// =====================================================================
__global__ __launch_bounds__(256, 2)
void gemm_scores(const u16* __restrict__ q16, const u16* __restrict__ k16,
                 const int* __restrict__ mask, float* __restrict__ sc,
                 int Sq, int bh0) {
    constexpr int BN = 128;
    __shared__ __align__(16) u16 As[128][64];
    __shared__ __align__(16) u16 Bs[BN][64];
    const int z = blockIdx.z, bh = bh0 + z, b = bh >> 3, h = bh & 7;
    const int m0 = blockIdx.y * 128, n0 = blockIdx.x * 128;
    const u16* Ab = q16 + ((size_t)b * Sq + m0) * 1024 + h * 128;
    const u16* Bb = k16 + ((size_t)b * 512 + n0) * 1024 + h * 128;
    const int lda16 = 1024, ldb16 = 1024, K16 = 128;
    TILE_PROLOGUE(BN)
    TILE_KLOOP(BN)
    const int lr = lane & 15, lq = lane >> 4;
#pragma unroll
    for (int i = 0; i < MI; ++i) {
        const int gi = m0 + mrow0 + i * 16 + lq * 4;
#pragma unroll
        for (int j = 0; j < 4; ++j) {
            const int gj = n0 + ncol0 + j * 16 + lr;
            const int mok = mask[b * 512 + gj];
#pragma unroll
            for (int r = 0; r < 4; ++r) {
                float s = acc[i][j][r] * 0.125f;
                if (mok == 0) s = -1e9f;
                sc[((size_t)z * Sq + gi + r) * 512 + gj] = s;
            }
        }
    }
}

// =====================================================================
// P@V: A = P split [Sq][1024] (chunk-local), B = Vt split [64][1024]
// out -> ao split-block u16 [rows][1024]: hi at h*64+d, lo at 512+h*64+d
// =====================================================================
__global__ __launch_bounds__(256, 2)
void gemm_pv(const u16* __restrict__ p16, const u16* __restrict__ vt,
             u16* __restrict__ ao, int Sq, int bh0) {
    constexpr int BN = 64;
    __shared__ __align__(16) u16 As[128][64];
    __shared__ __align__(16) u16 Bs[BN][64];
    const int z = blockIdx.y, bh = bh0 + z, b = bh >> 3, h = bh & 7;
    const int m0 = blockIdx.x * 128;
    const u16* Ab = p16 + ((size_t)z * Sq + m0) * 1024;
    const u16* Bb = vt + (size_t)bh * 64 * 1024;
    const int lda16 = 1024, ldb16 = 1024, K16 = 1024;
    TILE_PROLOGUE(BN)
    TILE_KLOOP(BN)
    const int lr = lane & 15, lq = lane >> 4;
#pragma unroll
    for (int i = 0; i < MI; ++i) {
        const int m = m0 + mrow0 + i * 16 + lq * 4;
#pragma unroll
        for (int j = 0; j < 4; ++j) {
            const int d = j * 16 + lr;
#pragma unroll
            for (int r = 0; r < 4; ++r) {
                u16 vh, vl; split1(acc[i][j][r], vh, vl);
                u16* row = ao + ((size_t)b * Sq + m + r) * 1024 + h * 64 + d;
                row[0]   = vh;
                row[512] = vl;
            }
        }
    }
}

// =====================================================================
// Weight transpose+split: W[K][N] f32 (row stride ldW) ->
// Wt[n][2K] u16: hi at k, lo at K+k. Rows n>=Nvalid zero-filled.
// z-offsets for fused QKVO staging.
// =====================================================================
__global__ __launch_bounds__(256)
void wtrans_kernel(const float* __restrict__ W, int ldW, int Nvalid, int K,
                   u16* __restrict__ Wt, int ldt16, int zsW, int zsT) {
    const float* Wz = W + (size_t)blockIdx.z * zsW;
    u16* Wtz = Wt + (size_t)blockIdx.z * zsT;
    __shared__ float T[32][33];
    const int n0 = blockIdx.x * 32, k0 = blockIdx.y * 32;
    const int tx = threadIdx.x & 31, ty = threadIdx.x >> 5;
#pragma unroll
    for (int it = 0; it < 4; ++it) {
        const int kk = ty + it * 8;
        const int n = n0 + tx;
        T[kk][tx] = (n < Nvalid) ? Wz[(size_t)(k0 + kk) * ldW + n] : 0.f;
    }
    __syncthreads();
#pragma unroll
    for (int it = 0; it < 4; ++it) {
        const int nn = ty + it * 8;
        u16 hh, ll; split1(T[tx][nn], hh, ll);
        u16* row = Wtz + (size_t)(n0 + nn) * ldt16;
        row[k0 + tx]     = hh;
        row[K + k0 + tx] = ll;
    }
}

// =====================================================================
// V transpose+split: v f32 [4096][512] -> vt u16 [bh][64][1024]
// vt[bh][d][j]=hi, vt[bh][d][512+j]=lo
// =====================================================================
__global__ __launch_bounds__(256)
void vtrans_kernel(const float* __restrict__ v, u16* __restrict__ vt) {
    const int jt = blockIdx.x;          // 8 j-tiles of 64
    const int bh = blockIdx.y;          // 64
    const int b = bh >> 3, h = bh & 7;
    __shared__ float T[64][65];
    const int tid = threadIdx.x;
    const int r = tid >> 2, c0 = (tid & 3) * 16;
    const float* src = v + ((size_t)b * 512 + jt * 64 + r) * 512 + h * 64 + c0;
#pragma unroll
    for (int u = 0; u < 4; ++u) {
        float4 f = *(const float4*)(src + u * 4);
        T[r][c0 + u * 4 + 0] = f.x; T[r][c0 + u * 4 + 1] = f.y;
        T[r][c0 + u * 4 + 2] = f.z; T[r][c0 + u * 4 + 3] = f.w;
    }
    __syncthreads();
    u16* dst = vt + ((size_t)bh * 64 + r) * 1024 + jt * 64 + c0;
#pragma unroll
    for (int u = 0; u < 16; ++u) {
        u16 hh, ll; split1(T[c0 + u][r], hh, ll);
        dst[u]       = hh;
        dst[u + 512] = ll;
    }
}

// =============================================================
// Embedding (f32 out)
// =============================================================
__global__ void embed_kernel(const int* __restrict__ tok, const float* __restrict__ emb,
                             const float* __restrict__ pe, float* __restrict__ out,
                             int S, int total) {
    int i = blockIdx.x * 256 + threadIdx.x;
    if (i >= total) return;
    int d  = i & 511;
    int bs = i >> 9;
    int s  = bs % S;
    int t  = tok[bs];
    out[i] = emb[(size_t)t * 512 + d] * 22.62741699796952f + pe[(size_t)s * 512 + d];
}

// =============================================================
// LayerNorm (torch variant) -> split-block u16 [row][1024]
// =============================================================
__global__ __launch_bounds__(256)
void layernorm_split(const float* __restrict__ x, const float* __restrict__ g,
                     const float* __restrict__ bta, u16* __restrict__ out16) {
    __shared__ float red[256];
    const int row = blockIdx.x, tid = threadIdx.x;
    const float* xr = x + (size_t)row * 512;
    float v0 = xr[tid], v1 = xr[tid + 256];
    red[tid] = v0 + v1;
    __syncthreads();
    for (int st = 128; st > 0; st >>= 1) { if (tid < st) red[tid] += red[tid + st]; __syncthreads(); }
    float mean = red[0] * (1.f / 512.f);
    __syncthreads();
    float d0 = v0 - mean, d1 = v1 - mean;
    red[tid] = d0 * d0 + d1 * d1;
    __syncthreads();
    for (int st = 128; st > 0; st >>= 1) { if (tid < st) red[tid] += red[tid + st]; __syncthreads(); }
    float var = red[0] * (1.f / 511.f);
    float inv = 1.f / (sqrtf(var) + 1e-6f);
    float o0 = g[tid] * d0 * inv + bta[tid];
    float o1 = g[tid + 256] * d1 * inv + bta[tid + 256];
    u16 h0, l0, h1, l1;
    split1(o0, h0, l0);
    split1(o1, h1, l1);
    u16* o = out16 + (size_t)row * 1024;
    o[tid]        = h0;
    o[tid + 256]  = h1;
    o[512 + tid]  = l0;
    o[768 + tid]  = l1;
}

// =============================================================
// Softmax over 512-rows, in place: reads f32, writes split u16
// =============================================================
__global__ __launch_bounds__(256)
void softmax_split(float* __restrict__ p) {
    __shared__ float red[256];
    const int row = blockIdx.x, tid = threadIdx.x;
    float* pr = p + (size_t)row * 512;
    float v0 = pr[tid], v1 = pr[tid + 256];
    red[tid] = fmaxf(v0, v1);
    __syncthreads();
    for (int st = 128; st > 0; st >>= 1) { if (tid < st) red[tid] = fmaxf(red[tid], red[tid + st]); __syncthreads(); }
    float mx = red[0];
    __syncthreads();
    float e0 = __expf(v0 - mx), e1 = __expf(v1 - mx);
    red[tid] = e0 + e1;
    __syncthreads();
    for (int st = 128; st > 0; st >>= 1) { if (tid < st) red[tid] += red[tid + st]; __syncthreads(); }
    float inv = 1.f / red[0];
    float p0 = e0 * inv, p1 = e1 * inv;
    u16 h0, l0, h1, l1;
    split1(p0, h0, l0);
    split1(p1, h1, l1);
    u16* pu = (u16*)pr;
    pu[tid]       = h0;
    pu[tid + 256] = h1;
    pu[512 + tid] = l0;
    pu[768 + tid] = l1;
}

// =============================================================
// In-place log_softmax on f32 rows of length N
// =============================================================
__global__ __launch_bounds__(256)
void logsoftmax_kernel(float* __restrict__ out, int N) {
    __shared__ float red[256];
    const int row = blockIdx.x, tid = threadIdx.x;
    float* pr = out + (size_t)row * N;
    float mx = -3.4e38f;
    for (int c = tid; c < N; c += 256) mx = fmaxf(mx, pr[c]);
    red[tid] = mx;
    __syncthreads();
    for (int st = 128; st > 0; st >>= 1) { if (tid < st) red[tid] = fmaxf(red[tid], red[tid + st]); __syncthreads(); }
    mx = red[0];
    __syncthreads();
    float s = 0.f;
    for (int c = tid; c < N; c += 256) s += __expf(pr[c] - mx);
    red[tid] = s;
    __syncthreads();
    for (int st = 128; st > 0; st >>= 1) { if (tid < st) red[tid] += red[tid + st]; __syncthreads(); }
    float ls = mx + __logf(red[0]);
    for (int c = tid; c < N; c += 256) pr[c] = pr[c] - ls;
}

// =============================================================
// Host orchestration — ws 64 MB (16,777,216 floats)
// layout (floats): x@0, h@2M, mem@4M, q@6M, k@8M, v@10M, sf@12M..16M
// =============================================================
extern "C" void kernel_launch(void* const* d_in, const int* in_sizes, int n_in,
                              void* d_out, int out_size, void* d_ws, size_t ws_size,
                              hipStream_t stream) {
    const int*   src       = (const int*)d_in[0];
    const int*   tgt       = (const int*)d_in[1];
    const int*   src_mask  = (const int*)d_in[2];
    const float* emb_src   = (const float*)d_in[4];
    const float* emb_tgt   = (const float*)d_in[5];
    const float* pe        = (const float*)d_in[6];
    const float* enc_qkvo_w = (const float*)d_in[7];
    const float* enc_qkvo_b = (const float*)d_in[8];
    const float* enc_ff_w1  = (const float*)d_in[9];
    const float* enc_ff_b1  = (const float*)d_in[10];
    const float* enc_ff_w2  = (const float*)d_in[11];
    const float* enc_ff_b2  = (const float*)d_in[12];
    const float* enc_ln_g   = (const float*)d_in[13];
    const float* enc_ln_b   = (const float*)d_in[14];
    const float* enc_norm_g = (const float*)d_in[15];
    const float* enc_norm_b = (const float*)d_in[16];
    const float* dec_qkvo_w = (const float*)d_in[17];
    const float* dec_qkvo_b = (const float*)d_in[18];
    const float* dec_ff_w1  = (const float*)d_in[19];
    const float* dec_ff_b1  = (const float*)d_in[20];
    const float* dec_ff_w2  = (const float*)d_in[21];
    const float* dec_ff_b2  = (const float*)d_in[22];
    const float* dec_ln_g   = (const float*)d_in[23];
    const float* dec_ln_b   = (const float*)d_in[24];
    const float* dec_norm_g = (const float*)d_in[25];
    const float* dec_norm_b = (const float*)d_in[26];
    const float* gen_w      = (const float*)d_in[27];
    const float* gen_b      = (const float*)d_in[28];

    float* ws   = (float*)d_ws;
    float* x    = ws;                       // f32 stream (enc x / dec y)
    u16*   h16  = (u16*)(ws + 2097152);     // split LN output
    float* memf = ws + 4194304;             // enc: Wt staging; later mem_split
    u16*   mem16 = (u16*)memf;
    float* qf   = ws + 6291456;
    u16*   q16  = (u16*)qf;
    float* kf   = ws + 8388608;
    u16*   k16  = (u16*)kf;
    float* vf   = ws + 10485760;
    u16*   ao16 = (u16*)vf;                 // ao reuses v slot (v dead after vtrans)
    float* sf   = ws + 12582912;            // 4M floats
    u16*   vt16 = (u16*)(sf + 2097152);     // 8MB V-transpose

    // ---------------- encoder ----------------
    const int totE = 8 * 512 * 512;
    embed_kernel<<<totE / 256, 256, 0, stream>>>(src, emb_src, pe, x, 512, totE);

    for (int l = 0; l < 8; ++l) {
        const float* wq = enc_qkvo_w + (size_t)l * 1048576;
        const float* bq = enc_qkvo_b + (size_t)l * 2048;
        u16* WtQ = mem16;                               // [2048][1024]
        wtrans_kernel<<<dim3(16, 16, 4), 256, 0, stream>>>(wq, 512, 512, 512, WtQ, 1024, 262144, 512 * 1024);
        layernorm_split<<<4096, 256, 0, stream>>>(x, enc_ln_g + (l * 2) * 512, enc_ln_b + (l * 2) * 512, h16);
        gemm_qkv<128, 2><<<dim3(12, 32), 256, 0, stream>>>(h16, 1024, WtQ, 1024, bq, (char*)qf, 1024);
        vtrans_kernel<<<dim3(8, 64), 256, 0, stream>>>(vf, vt16);
        for (int c = 0; c < 8; ++c) {
            gemm_scores<<<dim3(4, 4, 8), 256, 0, stream>>>(q16, k16, src_mask, sf, 512, c * 8);
            softmax_split<<<8 * 512, 256, 0, stream>>>(sf);
            gemm_pv<<<dim3(4, 8), 256, 0, stream>>>((const u16*)sf, vt16, ao16, 512, c * 8);
        }
        gemm_f32out<64, 1, 0><<<dim3(8, 32), 256, 0, stream>>>(ao16, 1024, WtQ + (size_t)1536 * 1024, 1024,
                                                               bq + 1536, x, 512, x, 512, 1024, 512);
        u16* WtF1 = mem16;                              // [2048][1024]
        u16* WtF2 = (u16*)(memf + 1048576);             // [512][4096]
        wtrans_kernel<<<dim3(64, 16, 1), 256, 0, stream>>>(enc_ff_w1 + (size_t)l * 1048576, 2048, 2048, 512, WtF1, 1024, 0, 0);
        wtrans_kernel<<<dim3(16, 64, 1), 256, 0, stream>>>(enc_ff_w2 + (size_t)l * 1048576, 512, 512, 2048, WtF2, 4096, 0, 0);
        layernorm_split<<<4096, 256, 0, stream>>>(x, enc_ln_g + (l * 2 + 1) * 512, enc_ln_b + (l * 2 + 1) * 512, h16);
        u16* mid16 = q16;                               // [4096][4096] u16 spans q,k,v,sf[0..2M)
        gemm_ff1<<<dim3(16, 32), 256, 0, stream>>>(h16, 1024, WtF1, 1024, enc_ff_b1 + l * 2048, mid16, 2048, 1024);
        gemm_f32out<64, 1, 0><<<dim3(8, 32), 256, 0, stream>>>(mid16, 4096, WtF2, 4096, enc_ff_b2 + l * 512,
                                                               x, 512, x, 512, 4096, 512);
    }
    layernorm_split<<<4096, 256, 0, stream>>>(x, enc_norm_g, enc_norm_b, mem16);  // memory (split)

    // ---------------- decoder ----------------
    float* y = x;
    const int totD = 8 * 256 * 512;
    embed_kernel<<<totD / 256, 256, 0, stream>>>(tgt, emb_tgt, pe, y, 256, totD);

    for (int l = 0; l < 8; ++l) {
        const float* wq = dec_qkvo_w + (size_t)l * 1048576;
        const float* bq = dec_qkvo_b + (size_t)l * 2048;
        u16* WtQ = (u16*)sf;                            // [2048][1024] in sf[0..1M)
        float* scd = sf + 1048576;                      // dec scores 8x256x512 f32
        wtrans_kernel<<<dim3(16, 16, 4), 256, 0, stream>>>(wq, 512, 512, 512, WtQ, 1024, 262144, 512 * 1024);
        layernorm_split<<<2048, 256, 0, stream>>>(y, dec_ln_g + (l * 2) * 512, dec_ln_b + (l * 2) * 512, h16);
        gemm_qkv<64, -1><<<dim3(8, 16), 256, 0, stream>>>(h16, 1024, WtQ, 1024, bq, (char*)qf, 1024);
        gemm_qkv<128, 1><<<dim3(8, 32), 256, 0, stream>>>(mem16, 1024, WtQ + (size_t)512 * 1024, 1024,
                                                          bq + 512, (char*)kf, 1024);
        vtrans_kernel<<<dim3(8, 64), 256, 0, stream>>>(vf, vt16);
        for (int c = 0; c < 8; ++c) {
            gemm_scores<<<dim3(4, 2, 8), 256, 0, stream>>>(q16, k16, src_mask, scd, 256, c * 8);
            softmax_split<<<8 * 256, 256, 0, stream>>>(scd);
            gemm_pv<<<dim3(2, 8), 256, 0, stream>>>((const u16*)scd, vt16, ao16, 256, c * 8);
        }
        gemm_f32out<64, 1, 0><<<dim3(8, 16), 256, 0, stream>>>(ao16, 1024, WtQ + (size_t)1536 * 1024, 1024,
                                                               bq + 1536, y, 512, y, 512, 1024, 512);
        u16* WtF1 = (u16*)sf;
        u16* WtF2 = (u16*)(sf + 1048576);
        wtrans_kernel<<<dim3(64, 16, 1), 256, 0, stream>>>(dec_ff_w1 + (size_t)l * 1048576, 2048, 2048, 512, WtF1, 1024, 0, 0);
        wtrans_kernel<<<dim3(16, 64, 1), 256, 0, stream>>>(dec_ff_w2 + (size_t)l * 1048576, 512, 512, 2048, WtF2, 4096, 0, 0);
        layernorm_split<<<2048, 256, 0, stream>>>(y, dec_ln_g + (l * 2 + 1) * 512, dec_ln_b + (l * 2 + 1) * 512, h16);
        u16* mid16 = q16;                               // [2048][4096] u16 spans q,k
        gemm_ff1<<<dim3(16, 16), 256, 0, stream>>>(h16, 1024, WtF1, 1024, dec_ff_b1 + l * 2048, mid16, 2048, 1024);
        gemm_f32out<64, 1, 0><<<dim3(8, 16), 256, 0, stream>>>(mid16, 4096, WtF2, 4096, dec_ff_b2 + l * 512,
                                                               y, 512, y, 512, 4096, 512);
    }
    layernorm_split<<<2048, 256, 0, stream>>>(y, dec_norm_g, dec_norm_b, h16);

    // ---------------- generator + log_softmax ----------------
    float* out = (float*)d_out;
    u16* WtG = (u16*)sf;                                // [<=8192][1024] per chunk
    const int c0s[4]    = {0, 8192, 16384, 24576};
    const int cns[4]    = {8192, 8192, 8192, 7425};
    const int cnpads[4] = {8192, 8192, 8192, 7552};
    for (int i = 0; i < 4; ++i) {
        wtrans_kernel<<<dim3(cnpads[i] / 32, 16, 1), 256, 0, stream>>>(gen_w + c0s[i], 32001, cns[i], 512, WtG, 1024, 0, 0);
        gemm_f32out<128, 0, 1><<<dim3(cnpads[i] / 128, 16), 256, 0, stream>>>(h16, 1024, WtG, 1024, gen_b + c0s[i],
                                                                              nullptr, 0, out + c0s[i], 32001, 1024, cns[i]);
    }
    logsoftmax_kernel<<<2048, 256, 0, stream>>>(out, 32001);
}